// Round 11
// baseline (679.599 us; speedup 1.0000x reference)
//
#include <hip/hip_runtime.h>
#include <stdint.h>

#define N_TOK 7200
#define N_PAD 7232      // 113*64
#define K_CODE 8912
#define K_PAD 8960      // 140*64
#define N_KT 140
#define MID 256
#define C_DIM 768
#define INV_TEMP (1.0f/0.07f)
#define INV_ETEMP 100.0f
#define MARGIN 0.02f
#define CAND_CAP 64
#define EPS_N 1e-12f

typedef __attribute__((ext_vector_type(8))) short short8;   // 8 bf16 (4 VGPRs)
typedef __attribute__((ext_vector_type(4))) float f32x4;

__device__ __forceinline__ unsigned short f2bf(float f) {
    unsigned u = __float_as_uint(f);
    u += 0x7fffu + ((u >> 16) & 1u);   // round-to-nearest-even
    return (unsigned short)(u >> 16);
}
__device__ __forceinline__ float bf2f(unsigned short h) {
    return __uint_as_float(((unsigned)h) << 16);
}
// non-temporal f32x4 store (native ext_vector type: accepted by the builtin)
__device__ __forceinline__ void nt_store4(float* p, float a, float b, float c, float d) {
    f32x4 v; v.x = a; v.y = b; v.z = c; v.w = d;
    __builtin_nontemporal_store(v, (f32x4*)p);
}

// ---------------- fused prep: ennorm | wsplit | xsplit | init ---------------
__global__ void k_prep(const float* __restrict__ emb,
                       float* __restrict__ en, unsigned short* __restrict__ en_h,
                       const float* __restrict__ W,
                       unsigned short* __restrict__ wt_h, unsigned short* __restrict__ wt_l,
                       const float* __restrict__ x,
                       unsigned short* __restrict__ xh_g, unsigned short* __restrict__ xl_g,
                       float* __restrict__ ap_acc, int* __restrict__ used,
                       float* __restrict__ acc4, int* __restrict__ ccnt) {
    __shared__ float sb[256];
    int b = blockIdx.x, t = threadIdx.x;
    if (b < K_CODE) {
        float v = emb[b * MID + t];
        sb[t] = v * v; __syncthreads();
        for (int s = 128; s > 0; s >>= 1) { if (t < s) sb[t] += sb[t + s]; __syncthreads(); }
        float nn = sqrtf(sb[0]);
        float o = v / fmaxf(nn, EPS_N);
        en[b * MID + t] = o;
        en_h[b * MID + t] = f2bf(o);
    } else if (b < K_CODE + 768) {
        int i = (b - K_CODE) * 256 + t;       // < C_DIM*MID exactly
        int c = i / MID, tc = i % MID;
        float v = W[i];
        unsigned short h = f2bf(v);
        unsigned short l = f2bf(v - bf2f(h));
        wt_h[tc * C_DIM + c] = h;
        wt_l[tc * C_DIM + c] = l;
    } else if (b < K_CODE + 768 + 5400) {
        // 5400*256*4 == 7200*768 exactly
        size_t i4 = ((size_t)(b - K_CODE - 768) * 256 + t) * 4;
        float4 v = *(const float4*)(x + i4);
        unsigned short h0 = f2bf(v.x), h1 = f2bf(v.y), h2 = f2bf(v.z), h3 = f2bf(v.w);
        *((ushort4*)(xh_g + i4)) = make_ushort4(h0, h1, h2, h3);
        *((ushort4*)(xl_g + i4)) = make_ushort4(f2bf(v.x - bf2f(h0)), f2bf(v.y - bf2f(h1)),
                                                f2bf(v.z - bf2f(h2)), f2bf(v.w - bf2f(h3)));
    } else {
        int i = (b - K_CODE - 768 - 5400) * 256 + t;
        if (i < K_CODE) { ap_acc[i] = 0.f; used[i] = 0; }
        if (i < N_TOK) ccnt[i] = 0;
        if (i < 4) acc4[i] = 0.f;
    }
}

// ---------------- z = x @ W_down via bf16x3 MFMA (fp32-quality) -------------
__global__ __launch_bounds__(256) void k_zgemm(const unsigned short* __restrict__ xh_g,
                                               const unsigned short* __restrict__ xl_g,
                                               const unsigned short* __restrict__ wt_h,
                                               const unsigned short* __restrict__ wt_l,
                                               float* __restrict__ zbuf) {
    __shared__ unsigned short ls[4 * 64 * 72];
    unsigned short* xh = ls;
    unsigned short* xl = ls + 64 * 72;
    unsigned short* wh = ls + 2 * 64 * 72;
    unsigned short* wl = ls + 3 * 64 * 72;
    int tid = threadIdx.x;
    int m0 = blockIdx.y * 64;
    int t0 = blockIdx.x * 64;
    int lane = tid & 63, wv = tid >> 6;
    int quad = lane >> 4, l15 = lane & 15;
    int mrow0 = (wv >> 1) * 32, ncol0 = (wv & 1) * 32;
    f32x4 acc[2][2] = {};

    for (int ch = 0; ch < 12; ch++) {
        int c0 = ch * 64;
        for (int it = 0; it < 2; it++) {
            int r = it * 32 + (tid >> 3);
            int cq = tid & 7;
            int gr = m0 + r;
            uint4 vh = make_uint4(0, 0, 0, 0), vl = make_uint4(0, 0, 0, 0);
            if (gr < N_TOK) {
                vh = ((const uint4*)xh_g)[(size_t)gr * (C_DIM / 8) + (c0 >> 3) + cq];
                vl = ((const uint4*)xl_g)[(size_t)gr * (C_DIM / 8) + (c0 >> 3) + cq];
            }
            *((uint4*)&xh[r * 72 + cq * 8]) = vh;
            *((uint4*)&xl[r * 72 + cq * 8]) = vl;
        }
        for (int it = 0; it < 2; it++) {
            int r = it * 32 + (tid >> 3);
            int cq = tid & 7;
            uint4 vh = ((const uint4*)wt_h)[(size_t)(t0 + r) * (C_DIM / 8) + (c0 >> 3) + cq];
            uint4 vl = ((const uint4*)wt_l)[(size_t)(t0 + r) * (C_DIM / 8) + (c0 >> 3) + cq];
            *((uint4*)&wh[r * 72 + cq * 8]) = vh;
            *((uint4*)&wl[r * 72 + cq * 8]) = vl;
        }
        __syncthreads();
        for (int ks = 0; ks < 2; ks++) {
            int co = ks * 32 + quad * 8;
            short8 ah0 = *((const short8*)&xh[(mrow0 + l15) * 72 + co]);
            short8 ah1 = *((const short8*)&xh[(mrow0 + 16 + l15) * 72 + co]);
            short8 al0 = *((const short8*)&xl[(mrow0 + l15) * 72 + co]);
            short8 al1 = *((const short8*)&xl[(mrow0 + 16 + l15) * 72 + co]);
            short8 bh0 = *((const short8*)&wh[(ncol0 + l15) * 72 + co]);
            short8 bh1 = *((const short8*)&wh[(ncol0 + 16 + l15) * 72 + co]);
            short8 bl0 = *((const short8*)&wl[(ncol0 + l15) * 72 + co]);
            short8 bl1 = *((const short8*)&wl[(ncol0 + 16 + l15) * 72 + co]);
            acc[0][0] = __builtin_amdgcn_mfma_f32_16x16x32_bf16(ah0, bh0, acc[0][0], 0, 0, 0);
            acc[0][1] = __builtin_amdgcn_mfma_f32_16x16x32_bf16(ah0, bh1, acc[0][1], 0, 0, 0);
            acc[1][0] = __builtin_amdgcn_mfma_f32_16x16x32_bf16(ah1, bh0, acc[1][0], 0, 0, 0);
            acc[1][1] = __builtin_amdgcn_mfma_f32_16x16x32_bf16(ah1, bh1, acc[1][1], 0, 0, 0);
            acc[0][0] = __builtin_amdgcn_mfma_f32_16x16x32_bf16(ah0, bl0, acc[0][0], 0, 0, 0);
            acc[0][1] = __builtin_amdgcn_mfma_f32_16x16x32_bf16(ah0, bl1, acc[0][1], 0, 0, 0);
            acc[1][0] = __builtin_amdgcn_mfma_f32_16x16x32_bf16(ah1, bl0, acc[1][0], 0, 0, 0);
            acc[1][1] = __builtin_amdgcn_mfma_f32_16x16x32_bf16(ah1, bl1, acc[1][1], 0, 0, 0);
            acc[0][0] = __builtin_amdgcn_mfma_f32_16x16x32_bf16(al0, bh0, acc[0][0], 0, 0, 0);
            acc[0][1] = __builtin_amdgcn_mfma_f32_16x16x32_bf16(al0, bh1, acc[0][1], 0, 0, 0);
            acc[1][0] = __builtin_amdgcn_mfma_f32_16x16x32_bf16(al1, bh0, acc[1][0], 0, 0, 0);
            acc[1][1] = __builtin_amdgcn_mfma_f32_16x16x32_bf16(al1, bh1, acc[1][1], 0, 0, 0);
        }
        __syncthreads();
    }
    for (int i = 0; i < 2; i++)
        for (int j = 0; j < 2; j++)
            for (int r = 0; r < 4; r++) {
                int gr = m0 + mrow0 + i * 16 + quad * 4 + r;
                int gc = t0 + ncol0 + j * 16 + l15;
                if (gr < N_TOK) zbuf[(size_t)gr * MID + gc] = acc[i][j][r];
            }
}

// ---------------- z + b -> l2norm -> zn (in place) + zn_h -------------------
__global__ void k_znorm(float* __restrict__ zbuf, const float* __restrict__ b_down,
                        unsigned short* __restrict__ zn_h) {
    int n = blockIdx.x, t = threadIdx.x;
    float v = zbuf[(size_t)n * MID + t] + b_down[t];
    __shared__ float sb[256];
    sb[t] = v * v; __syncthreads();
    for (int s = 128; s > 0; s >>= 1) { if (t < s) sb[t] += sb[t + s]; __syncthreads(); }
    float nn = sqrtf(sb[0]);
    float o = v / fmaxf(nn, EPS_N);
    zbuf[(size_t)n * MID + t] = o;
    zn_h[(size_t)n * MID + t] = f2bf(o);
}

// ---------------- SINGLE d-GEMM: stats -> part4, p_t -> out1 ----------------
// p_t = exp((vmin_tile - d) * INV_TEMP)  (<= 1), stored via coalesced float4
// regular stores so out1 (~257 MB) stays L3-resident for k_fix's read.
__global__ __launch_bounds__(256) void k_dmain(const unsigned short* __restrict__ zn_h,
                                               const unsigned short* __restrict__ en_h,
                                               float* __restrict__ part4,
                                               float* __restrict__ out1) {
    __shared__ __align__(16) char smem[32768];
    char* atB = smem;            // A: 64 rows x 256 B (128 bf16), swizzled
    char* btB = smem + 16384;    // B: same
    int tid = threadIdx.x;
    int kt = blockIdx.x, mt = blockIdx.y;
    int m0 = mt * 64, k0c = kt * 64;
    int lane = tid & 63, wv = tid >> 6;
    int quad = lane >> 4, l15 = lane & 15;
    int mrow0 = (wv >> 1) * 32, ncol0 = (wv & 1) * 32;
    f32x4 acc[2][2] = {};

    for (int ch = 0; ch < 2; ch++) {
        int c0 = ch * 128;
        for (int it = 0; it < 4; it++) {
            int r = it * 16 + (tid >> 4);
            int cq = tid & 15;
            uint4 va = ((const uint4*)zn_h)[(size_t)(m0 + r) * (MID / 8) + (c0 >> 3) + cq];
            uint4 vb = ((const uint4*)en_h)[(size_t)(k0c + r) * (MID / 8) + (c0 >> 3) + cq];
            int boff = r * 256 + ((cq * 16) ^ ((r & 7) << 4));
            *((uint4*)(atB + boff)) = va;
            *((uint4*)(btB + boff)) = vb;
        }
        __syncthreads();
        for (int ks = 0; ks < 4; ks++) {
            int co = ks * 64 + quad * 16;    // byte col base within row
            int ra0 = mrow0 + l15,      ra1 = mrow0 + 16 + l15;
            int rb0 = ncol0 + l15,      rb1 = ncol0 + 16 + l15;
            short8 a0 = *((const short8*)(atB + ra0 * 256 + (co ^ ((ra0 & 7) << 4))));
            short8 a1 = *((const short8*)(atB + ra1 * 256 + (co ^ ((ra1 & 7) << 4))));
            short8 b0 = *((const short8*)(btB + rb0 * 256 + (co ^ ((rb0 & 7) << 4))));
            short8 b1 = *((const short8*)(btB + rb1 * 256 + (co ^ ((rb1 & 7) << 4))));
            acc[0][0] = __builtin_amdgcn_mfma_f32_16x16x32_bf16(a0, b0, acc[0][0], 0, 0, 0);
            acc[0][1] = __builtin_amdgcn_mfma_f32_16x16x32_bf16(a0, b1, acc[0][1], 0, 0, 0);
            acc[1][0] = __builtin_amdgcn_mfma_f32_16x16x32_bf16(a1, b0, acc[1][0], 0, 0, 0);
            acc[1][1] = __builtin_amdgcn_mfma_f32_16x16x32_bf16(a1, b1, acc[1][1], 0, 0, 0);
        }
        __syncthreads();
    }

    // ---- epilogue: d-tile in LDS, stats + vmin record, then p_t store ----
    float* sd  = (float*)smem;                 // 64*68 floats
    float* vmn = sd + 64 * 68;                 // 64 floats

    for (int i = 0; i < 2; i++)
        for (int j = 0; j < 2; j++)
            for (int r = 0; r < 4; r++) {
                int lr = mrow0 + i * 16 + quad * 4 + r;
                int lc = ncol0 + j * 16 + l15;
                int gc = k0c + lc;
                float dv = (gc < K_CODE) ? (2.f - 2.f * acc[i][j][r]) : 1e30f;
                sd[lr * 68 + lc] = dv;
            }
    __syncthreads();

    {   // stats: 4 waves x 16 rows, 4 lanes/row, 16 values/lane
        int rloc = wv * 16 + (lane >> 2);
        const float* rowp = sd + rloc * 68 + (lane & 3) * 16;
        float vals[16];
        float vmin = 1e30f;
        #pragma unroll
        for (int i = 0; i < 16; i++) { vals[i] = rowp[i]; vmin = fminf(vmin, vals[i]); }
        vmin = fminf(vmin, __shfl_xor(vmin, 1));
        vmin = fminf(vmin, __shfl_xor(vmin, 2));
        float st = 0.f, s1 = 0.f, s2 = 0.f;
        #pragma unroll
        for (int i = 0; i < 16; i++) {
            float dd = vmin - vals[i];
            st += __expf(dd * INV_TEMP);
            float te = dd * INV_ETEMP;
            float e = __expf(te);
            s1 += e; s2 += e * te;
        }
        st += __shfl_xor(st, 1); st += __shfl_xor(st, 2);
        s1 += __shfl_xor(s1, 1); s1 += __shfl_xor(s1, 2);
        s2 += __shfl_xor(s2, 1); s2 += __shfl_xor(s2, 2);
        if ((lane & 3) == 0) {
            vmn[rloc] = vmin;
            int gr = m0 + rloc;
            if (gr < N_TOK)
                nt_store4(part4 + ((size_t)gr * N_KT + kt) * 4, vmin, st, s1, s2);
        }
    }
    __syncthreads();

    // p_t store: coalesced float4, regular (cached) stores
    #pragma unroll
    for (int it = 0; it < 4; it++) {
        int idx = it * 256 + tid;
        int lr = idx >> 4, c4 = idx & 15;
        int gr = m0 + lr;
        if (gr >= N_TOK) continue;
        int gc = k0c + c4 * 4;
        if (gc >= K_CODE) continue;           // K_CODE % 4 == 0: fully in or out
        float4 v = *((const float4*)(sd + lr * 68 + c4 * 4));
        float vm = vmn[lr];
        float4 p;
        p.x = __expf((vm - v.x) * INV_TEMP);
        p.y = __expf((vm - v.y) * INV_TEMP);
        p.z = __expf((vm - v.z) * INV_TEMP);
        p.w = __expf((vm - v.w) * INV_TEMP);
        *((float4*)(out1 + (size_t)gr * K_CODE + gc)) = p;
    }
}

// ---------------- combine 140 tile-partials per row -------------------------
__global__ void k_combine(const float4* __restrict__ part4,
                          float* __restrict__ rs_m, float* __restrict__ rs_ist,
                          float* __restrict__ rs_is1,
                          float* __restrict__ acc4) {
    int sub = threadIdx.x >> 6;
    int row = blockIdx.x * 4 + sub;
    int l = threadIdx.x & 63;
    float4 pv[3];
    float m = 1e30f;
    #pragma unroll
    for (int c = 0; c < 3; c++) {
        int t = l + c * 64;
        pv[c] = (t < N_KT) ? part4[(size_t)row * N_KT + t] : make_float4(1e30f, 0.f, 0.f, 0.f);
        m = fminf(m, pv[c].x);
    }
    #pragma unroll
    for (int s = 1; s < 64; s <<= 1) m = fminf(m, __shfl_xor(m, s));
    float st = 0.f, s1 = 0.f, s2 = 0.f;
    #pragma unroll
    for (int c = 0; c < 3; c++) {
        float mb = pv[c].x;
        int t = l + c * 64;
        if (t < N_KT && mb < 1e29f) {
            float dT = (m - mb) * INV_TEMP;
            st += __expf(dT) * pv[c].y;
            float dE = (m - mb) * INV_ETEMP;
            float e = __expf(dE);
            s1 += e * pv[c].z;
            s2 += e * (pv[c].w + dE * pv[c].z);
        }
    }
    #pragma unroll
    for (int s = 1; s < 64; s <<= 1) {
        st += __shfl_xor(st, s);
        s1 += __shfl_xor(s1, s);
        s2 += __shfl_xor(s2, s);
    }
    if (l == 0) {
        rs_m[row] = m;
        rs_ist[row] = 1.f / st;
        rs_is1[row] = 1.f / s1;
        atomicAdd(&acc4[1], s2 / s1 - __logf(s1));
    }
}

// ---------------- streaming fixup: p_t -> p in place + cands + col sums -----
// p       = p_t * s,  s  = exp((m_row - vmin)*INV_T) * ist        (<= ist)
// cand    : p_t >= th, th = exp((vmin - m_row - MARGIN)*INV_T)     (monotone-eq d<=m+MARGIN)
// ce term : exp((m_row-d)*INV_E) = p_t^7 * exp((m_row-vmin)*INV_E) (T/E = 7 exactly)
__global__ __launch_bounds__(256) void k_fix(float* __restrict__ out1,
                                             const float* __restrict__ part4,
                                             const float* __restrict__ rs_m,
                                             const float* __restrict__ rs_ist,
                                             const float* __restrict__ rs_is1,
                                             float* __restrict__ ap_acc,
                                             int* __restrict__ ccnt,
                                             int* __restrict__ cand) {
    __shared__ float sS[128 * 4], sT[128 * 4], sE[128 * 4];
    __shared__ float colacc[4 * 256];
    int ct = blockIdx.x, rt = blockIdx.y;
    int r0 = rt * 128, c0 = ct * 256;
    int t = threadIdx.x;
    for (int p = t; p < 512; p += 256) {
        int row = p >> 2, k4 = p & 3;
        int gr = r0 + row;
        float s = 0.f, th = 1e30f, e = 0.f;
        if (gr < N_TOK) {
            int kt = (c0 >> 6) + k4;                         // < 140
            float vmin = part4[((size_t)gr * N_KT + kt) * 4];
            float m = rs_m[gr];
            s  = __expf((m - vmin) * INV_TEMP) * rs_ist[gr];
            th = __expf((vmin - m - MARGIN) * INV_TEMP);
            e  = __expf((m - vmin) * INV_ETEMP) * rs_is1[gr];
        }
        sS[p] = s; sT[p] = th; sE[p] = e;
    }
    __syncthreads();
    int g = t >> 6;                 // 0..3 (32 rows each)
    int colq = (t & 63) * 4;        // 0..252
    int k4 = colq >> 6;
    int gc = c0 + colq;
    float ce0 = 0.f, ce1 = 0.f, ce2 = 0.f, ce3 = 0.f;
    if (gc < K_CODE) {
        for (int i = 0; i < 32; i++) {
            int lr = g * 32 + i;
            int gr = r0 + lr;
            if (gr >= N_TOK) break;
            size_t base = (size_t)gr * K_CODE + gc;
            float4 pt = *(const float4*)(out1 + base);
            int idx = lr * 4 + k4;
            float s = sS[idx], th = sT[idx], e = sE[idx];
            nt_store4(out1 + base, pt.x * s, pt.y * s, pt.z * s, pt.w * s);
            if (pt.x >= th) { int p = atomicAdd(&ccnt[gr], 1); if (p < CAND_CAP) cand[gr * CAND_CAP + p] = gc + 0; }
            if (pt.y >= th) { int p = atomicAdd(&ccnt[gr], 1); if (p < CAND_CAP) cand[gr * CAND_CAP + p] = gc + 1; }
            if (pt.z >= th) { int p = atomicAdd(&ccnt[gr], 1); if (p < CAND_CAP) cand[gr * CAND_CAP + p] = gc + 2; }
            if (pt.w >= th) { int p = atomicAdd(&ccnt[gr], 1); if (p < CAND_CAP) cand[gr * CAND_CAP + p] = gc + 3; }
            float a, a2, a4;
            a = pt.x; a2 = a * a; a4 = a2 * a2; ce0 += a4 * a2 * a * e;
            a = pt.y; a2 = a * a; a4 = a2 * a2; ce1 += a4 * a2 * a * e;
            a = pt.z; a2 = a * a; a4 = a2 * a2; ce2 += a4 * a2 * a * e;
            a = pt.w; a2 = a * a; a4 = a2 * a2; ce3 += a4 * a2 * a * e;
        }
    }
    colacc[g * 256 + colq + 0] = ce0;
    colacc[g * 256 + colq + 1] = ce1;
    colacc[g * 256 + colq + 2] = ce2;
    colacc[g * 256 + colq + 3] = ce3;
    __syncthreads();
    {
        float ssum = colacc[t] + colacc[256 + t] + colacc[512 + t] + colacc[768 + t];
        int c = c0 + t;
        if (c < K_CODE) atomicAdd(&ap_acc[c], ssum);
    }
}

// ---------------- exact fp32 argmin over candidates + out0 fused ------------
__global__ void k_refine(const float* __restrict__ zn, const float* __restrict__ en,
                         const int* __restrict__ ccnt, const int* __restrict__ cand,
                         int* __restrict__ idxb, int* __restrict__ used,
                         float* __restrict__ acc4, float* __restrict__ out0) {
    int n = blockIdx.x * 4 + (threadIdx.x >> 6);
    int lane = threadIdx.x & 63;
    if (n >= N_TOK) return;
    int cnt = ccnt[n];
    if (cnt > CAND_CAP) cnt = CAND_CAP;
    float4 a = ((const float4*)(zn + (size_t)n * MID))[lane];
    float best = 1e30f; int bj = K_CODE;
    for (int c = 0; c < cnt; c++) {
        int code = cand[n * CAND_CAP + c];
        float4 b = ((const float4*)(en + (size_t)code * MID))[lane];
        float s = a.x * b.x + a.y * b.y + a.z * b.z + a.w * b.w;
        #pragma unroll
        for (int off = 1; off < 64; off <<= 1) s += __shfl_xor(s, off);
        float dist = 2.f - 2.f * s;
        if (dist < best || (dist == best && code < bj)) { best = dist; bj = code; }
    }
    float4 b = ((const float4*)(en + (size_t)bj * MID))[lane];
    nt_store4(out0 + (size_t)n * MID + lane * 4, b.x, b.y, b.z, b.w);
    float dx = b.x - a.x, dy = b.y - a.y, dz = b.z - a.z, dw = b.w - a.w;
    float sq = dx * dx + dy * dy + dz * dz + dw * dw;
    #pragma unroll
    for (int off = 32; off > 0; off >>= 1) sq += __shfl_down(sq, off);
    if (lane == 0) {
        idxb[n] = bj;
        used[bj] = 1;
        atomicAdd(&acc4[0], sq);
    }
}

// ---------------- final scalars ---------------------------------------------
__global__ void k_scal(const int* __restrict__ used, const float* __restrict__ ap_acc,
                       const float* __restrict__ acc4, float* __restrict__ outs) {
    int t = threadIdx.x;
    float uSum = 0.f, aeSum = 0.f;
    for (int k = t; k < K_CODE; k += 256) {
        uSum += (float)used[k];
        float ap = ap_acc[k] * (1.0f / (float)N_TOK);
        aeSum += ap * __logf(ap + 1e-5f);
    }
    __shared__ float sb[256];
    sb[t] = uSum; __syncthreads();
    for (int s = 128; s > 0; s >>= 1) { if (t < s) sb[t] += sb[t + s]; __syncthreads(); }
    uSum = sb[0];
    __syncthreads(); sb[t] = aeSum; __syncthreads();
    for (int s = 128; s > 0; s >>= 1) { if (t < s) sb[t] += sb[t + s]; __syncthreads(); }
    aeSum = sb[0];
    if (t == 0) {
        outs[0] = uSum / (float)K_CODE;
        float vq = acc4[0] / (float)((size_t)N_TOK * MID);
        outs[1] = vq;
        outs[2] = vq;
        outs[3] = -(acc4[1] / (float)N_TOK) + aeSum;
    }
}

extern "C" void kernel_launch(void* const* d_in, const int* in_sizes, int n_in,
                              void* d_out, int out_size, void* d_ws, size_t ws_size,
                              hipStream_t stream) {
    const float* x   = (const float*)d_in[0];
    const float* W   = (const float*)d_in[1];
    const float* b   = (const float*)d_in[2];
    const float* emb = (const float*)d_in[3];

    float* out  = (float*)d_out;
    float* out0 = out;                                                  // [7200*256]
    float* out1 = out + (size_t)N_TOK * MID;                            // probs (p_t first)
    float* outs = out + (size_t)N_TOK * MID + (size_t)N_TOK * K_CODE;   // 4 scalars

    char* w = (char*)d_ws;
    size_t off = 0;
    auto carve = [&](size_t bytes) { void* p = w + off; off += (bytes + 255) & ~(size_t)255; return p; };
    float*          zn    = (float*)         carve((size_t)N_PAD * MID * 4);
    float*          en    = (float*)         carve((size_t)K_PAD * MID * 4);
    unsigned short* zn_h  = (unsigned short*)carve((size_t)N_PAD * MID * 2);
    unsigned short* en_h  = (unsigned short*)carve((size_t)K_PAD * MID * 2);
    unsigned short* wt_h  = (unsigned short*)carve((size_t)MID * C_DIM * 2);
    unsigned short* wt_l  = (unsigned short*)carve((size_t)MID * C_DIM * 2);
    unsigned short* xh_g  = (unsigned short*)carve((size_t)N_TOK * C_DIM * 2);
    unsigned short* xl_g  = (unsigned short*)carve((size_t)N_TOK * C_DIM * 2);
    float*          part4 = (float*)         carve((size_t)N_TOK * N_KT * 16);
    float*          rs_m  = (float*)         carve((size_t)N_TOK * 4);
    float*          rs_ist= (float*)         carve((size_t)N_TOK * 4);
    float*          rs_is1= (float*)         carve((size_t)N_TOK * 4);
    int*            ccnt  = (int*)           carve((size_t)N_TOK * 4);
    int*            cand  = (int*)           carve((size_t)N_TOK * CAND_CAP * 4);
    int*            idxb  = (int*)           carve((size_t)N_TOK * 4);
    float*          ap_acc= (float*)         carve((size_t)K_CODE * 4);
    int*            used  = (int*)           carve((size_t)K_CODE * 4);
    float*          acc4  = (float*)         carve(16);
    (void)ws_size; (void)in_sizes; (void)n_in; (void)out_size;

    k_prep   <<<K_CODE + 768 + 5400 + 35, 256, 0, stream>>>(emb, en, en_h, W, wt_h, wt_l,
                                                            x, xh_g, xl_g,
                                                            ap_acc, used, acc4, ccnt);
    k_zgemm  <<<dim3(4, 113), 256, 0, stream>>>(xh_g, xl_g, wt_h, wt_l, zn);
    k_znorm  <<<N_TOK, 256, 0, stream>>>(zn, b, zn_h);
    k_dmain  <<<dim3(N_KT, 113), 256, 0, stream>>>(zn_h, en_h, part4, out1);
    k_combine<<<N_TOK / 4, 256, 0, stream>>>((const float4*)part4, rs_m, rs_ist, rs_is1, acc4);
    k_fix    <<<dim3(35, 57), 256, 0, stream>>>(out1, part4, rs_m, rs_ist, rs_is1, ap_acc, ccnt, cand);
    k_refine <<<N_TOK / 4, 256, 0, stream>>>(zn, en, ccnt, cand, idxb, used, acc4, out0);
    k_scal   <<<1, 256, 0, stream>>>(used, ap_acc, acc4, outs);
}